// Round 8
// baseline (3358.131 us; speedup 1.0000x reference)
//
#include <hip/hip_runtime.h>
#include <hip/hip_bf16.h>

#define B_ 64
#define T_ 2048
#define DIN_ 128
#define H_ 256
#define DOUT_ 128

typedef __bf16 bf16x8 __attribute__((ext_vector_type(8)));
typedef unsigned short u16x8 __attribute__((ext_vector_type(8)));
typedef unsigned int u32x2 __attribute__((ext_vector_type(2)));
typedef unsigned int u32x4 __attribute__((ext_vector_type(4)));
typedef float f32x4 __attribute__((ext_vector_type(4)));

// Inline-asm MFMA with weights forced into ARCH VGPRs ("v") -> no AGPR banking,
// no v_accvgpr shuttling. Hazard discipline (validated R5/R6):
//  FIRST embeds 2 leading s_nop (VALU-write -> MFMA SrcC read needs 2 waits);
//  MID needs 0 waits (C->C chaining, full rate);
//  LAST of each chain is the compiler intrinsic so LLVM inserts the
//  MFMA-write -> VALU-read wait states itself.
#define MFMA_FIRST(acc, wgt, st) \
    asm volatile("s_nop 1\n\ts_nop 1\n\tv_mfma_f32_16x16x32_bf16 %0, %1, %2, %0" \
                 : "+v"(acc) : "v"(wgt), "v"(st))
#define MFMA_MID(acc, wgt, st) \
    asm volatile("v_mfma_f32_16x16x32_bf16 %0, %1, %2, %0" \
                 : "+v"(acc) : "v"(wgt), "v"(st))

static __device__ __forceinline__ unsigned short f2bf(float f) {
    union { float f; unsigned u; } v; v.f = f;
    unsigned r = v.u + 0x7FFFu + ((v.u >> 16) & 1u);   // RNE
    return (unsigned short)(r >> 16);
}
static __device__ __forceinline__ unsigned cvt_pk_bf16(float lo, float hi) {
    unsigned r;
    asm("v_cvt_pk_bf16_f32 %0, %1, %2" : "=v"(r) : "v"(lo), "v"(hi));
    return r;
}
static __device__ __forceinline__ float bfbits_lo(unsigned w) {
    union { unsigned u; float f; } v; v.u = w << 16; return v.f;
}
static __device__ __forceinline__ float bfbits_hi(unsigned w) {
    union { unsigned u; float f; } v; v.u = w & 0xFFFF0000u; return v.f;
}
static __device__ __forceinline__ float tanh_fast(float x) {
    // tanh(x) = 1 - 2/(exp2(2*log2e*x)+1); branch-free, no clamp, no NaN
    float e = __builtin_amdgcn_exp2f(2.885390081777927f * x);
    float r = __builtin_amdgcn_rcpf(e + 1.0f);
    return __builtin_fmaf(-2.0f, r, 1.0f);
}
static __device__ __forceinline__ bf16x8 ld8f_bf(const float* p) {
    float4 a = *(const float4*)p;
    float4 b = *(const float4*)(p + 4);
    u32x4 u;
    u[0] = cvt_pk_bf16(a.x, a.y);
    u[1] = cvt_pk_bf16(a.z, a.w);
    u[2] = cvt_pk_bf16(b.x, b.y);
    u[3] = cvt_pk_bf16(b.z, b.w);
    return __builtin_bit_cast(bf16x8, u);
}

// -------- kernel 1 (swapped): Pre0[t][b][n] = b0[n] + sum_k x[b][t][k]*Wx0[n][k]
__global__ __launch_bounds__(256) void k_pre(const float* __restrict__ x,
                                             const float* __restrict__ Wx0,
                                             const float* __restrict__ b0,
                                             unsigned short* __restrict__ Pre0) {
    const int t  = blockIdx.x;
    const int bc = blockIdx.y;
    const int w  = threadIdx.x >> 6;
    const int l  = threadIdx.x & 63;
    const int lr = l & 15, lg = l >> 4;

    bf16x8 af[4];
    const float* xrow = x + ((size_t)(bc * 16 + lr) * T_ + t) * DIN_ + lg * 8;
#pragma unroll
    for (int kk = 0; kk < 4; kk++) af[kk] = ld8f_bf(xrow + kk * 32);

    unsigned short* op = Pre0 + ((size_t)t * B_ + bc * 16 + lr) * H_;

#pragma unroll
    for (int i = 0; i < 4; i++) {
        const int n0 = (w + 4 * i) * 16;
        const float* wrow = Wx0 + (size_t)(n0 + lr) * DIN_ + lg * 8;
        bf16x8 bfr[4];
#pragma unroll
        for (int kk = 0; kk < 4; kk++) bfr[kk] = ld8f_bf(wrow + kk * 32);
        float4 bv = *(const float4*)&b0[n0 + lg * 4];
        f32x4 acc = { bv.x, bv.y, bv.z, bv.w };
#pragma unroll
        for (int kk = 0; kk < 4; kk++)
            acc = __builtin_amdgcn_mfma_f32_16x16x32_bf16(bfr[kk], af[kk], acc, 0, 0, 0);
        u32x2 pk;
        pk[0] = cvt_pk_bf16(acc[0], acc[1]);
        pk[1] = cvt_pk_bf16(acc[2], acc[3]);
        *(u32x2*)&op[n0 + lg * 4] = pk;
    }
}

// -------- kernel 2: sequential scan. 64 blocks x ONE batch row; 8 waves x 32 n.
// M=1: lane-groups read the SAME state chunk (LDS broadcast, 0 conflicts).
// waves_per_eu(2,2) forces the allocator to the full 256-reg/wave budget at
// 2 waves/SIMD: 192 weight VGPRs + ~55 working set fit -> no spills (R6's bug).
__global__ __launch_bounds__(512)
__attribute__((amdgpu_waves_per_eu(2, 2)))
void k_scan(const float* __restrict__ h0in,
            const float* __restrict__ Wh0,
            const float* __restrict__ Wx1,
            const float* __restrict__ Wh1,
            const float* __restrict__ b1,
            const unsigned short* __restrict__ Pre0,
            unsigned short* __restrict__ H1) {
    const int b   = blockIdx.x;            // one batch row per block
    const int tid = threadIdx.x;
    const int w   = tid >> 6, l = tid & 63;
    const int lr  = l & 15, lg = l >> 4;
    const int n0  = w * 32;

    __shared__ __align__(16) unsigned short h0s[2][256];
    __shared__ __align__(16) unsigned short h1s[2][256];

    // weight fragments: lane = W[n = n0+u*16+lr][k = kk*32+lg*8 .. +7]
    bf16x8 wh0f[2][8], wx1f[2][8], wh1f[2][8];
#pragma unroll
    for (int u = 0; u < 2; u++) {
        const int n = n0 + u * 16 + lr;
#pragma unroll
        for (int kk = 0; kk < 8; kk++) {
            const int k0 = kk * 32 + lg * 8;
            wh0f[u][kk] = ld8f_bf(Wh0 + (size_t)n * H_ + k0);
            wx1f[u][kk] = ld8f_bf(Wx1 + (size_t)n * H_ + k0);
            wh1f[u][kk] = ld8f_bf(Wh1 + (size_t)n * H_ + k0);
        }
    }
    float4 b1q0 = *(const float4*)&b1[n0 + lg * 4];
    float4 b1q1 = *(const float4*)&b1[n0 + 16 + lg * 4];

    // init state (linear, no swizzle)
    if (tid < 256) {
        h0s[0][tid] = f2bf(h0in[(size_t)b * H_ + tid]);
        h1s[0][tid] = f2bf(h0in[(size_t)(B_ + b) * H_ + tid]);
    }

    // Pre0 / H1 pointers (uniform across lr within a lane-group)
    const unsigned short* prep = Pre0 + (size_t)b * H_ + n0 + lg * 4;
    unsigned short* h1p = H1 + (size_t)b * H_ + n0 + lg * 4;
    u32x2 pv0 = *(const u32x2*)prep;
    u32x2 pv1 = *(const u32x2*)(prep + 16);
    prep += B_ * H_;

    __syncthreads();

    int cur = 0;
    for (int t = 0; t < T_; t++) {
        const int nxt = cur ^ 1;
        // ---- layer 0: h0n^T = Wh0 . h0^T + Pre0^T ; 2 C->C chains
        f32x4 a0, a1;
        a0[0] = bfbits_lo(pv0[0]); a0[1] = bfbits_hi(pv0[0]);
        a0[2] = bfbits_lo(pv0[1]); a0[3] = bfbits_hi(pv0[1]);
        a1[0] = bfbits_lo(pv1[0]); a1[1] = bfbits_hi(pv1[0]);
        a1[2] = bfbits_lo(pv1[1]); a1[3] = bfbits_hi(pv1[1]);
        // prefetch next step's Pre0 (tail over-read lands in H1 region, harmless)
        pv0 = *(const u32x2*)prep;
        pv1 = *(const u32x2*)(prep + 16);
        prep += B_ * H_;
#pragma unroll
        for (int kk = 0; kk < 8; kk++) {
            bf16x8 s = __builtin_bit_cast(bf16x8, *(const u16x8*)&h0s[cur][kk * 32 + lg * 8]);
            if (kk == 0) {
                MFMA_FIRST(a0, wh0f[0][0], s);
                MFMA_FIRST(a1, wh0f[1][0], s);
            } else if (kk < 7) {
                MFMA_MID(a0, wh0f[0][kk], s);
                MFMA_MID(a1, wh0f[1][kk], s);
            } else {
                a0 = __builtin_amdgcn_mfma_f32_16x16x32_bf16(wh0f[0][7], s, a0, 0, 0, 0);
                a1 = __builtin_amdgcn_mfma_f32_16x16x32_bf16(wh0f[1][7], s, a1, 0, 0, 0);
            }
        }
        u32x2 pk0, pk1;
        pk0[0] = cvt_pk_bf16(tanh_fast(a0[0]), tanh_fast(a0[1]));
        pk0[1] = cvt_pk_bf16(tanh_fast(a0[2]), tanh_fast(a0[3]));
        pk1[0] = cvt_pk_bf16(tanh_fast(a1[0]), tanh_fast(a1[1]));
        pk1[1] = cvt_pk_bf16(tanh_fast(a1[2]), tanh_fast(a1[3]));
        if (lr == 0) {
            *(u32x2*)&h0s[nxt][n0 + lg * 4] = pk0;
            *(u32x2*)&h0s[nxt][n0 + 16 + lg * 4] = pk1;
        }

        __syncthreads();   // single barrier per step (other pairs ordered by next one)

        // ---- layer 1: h1n^T = Wx1 . h0n^T + Wh1 . h1^T + b1 ; 2 dual-source chains
        f32x4 d0 = { b1q0.x, b1q0.y, b1q0.z, b1q0.w };
        f32x4 d1 = { b1q1.x, b1q1.y, b1q1.z, b1q1.w };
#pragma unroll
        for (int kk = 0; kk < 8; kk++) {
            bf16x8 s0 = __builtin_bit_cast(bf16x8, *(const u16x8*)&h0s[nxt][kk * 32 + lg * 8]);
            bf16x8 s1 = __builtin_bit_cast(bf16x8, *(const u16x8*)&h1s[cur][kk * 32 + lg * 8]);
            if (kk == 0) {
                MFMA_FIRST(d0, wx1f[0][0], s0);
                MFMA_FIRST(d1, wx1f[1][0], s0);
                MFMA_MID(d0, wh1f[0][0], s1);
                MFMA_MID(d1, wh1f[1][0], s1);
            } else if (kk < 7) {
                MFMA_MID(d0, wx1f[0][kk], s0);
                MFMA_MID(d1, wx1f[1][kk], s0);
                MFMA_MID(d0, wh1f[0][kk], s1);
                MFMA_MID(d1, wh1f[1][kk], s1);
            } else {
                MFMA_MID(d0, wx1f[0][7], s0);
                MFMA_MID(d1, wx1f[1][7], s0);
                d0 = __builtin_amdgcn_mfma_f32_16x16x32_bf16(wh1f[0][7], s1, d0, 0, 0, 0);
                d1 = __builtin_amdgcn_mfma_f32_16x16x32_bf16(wh1f[1][7], s1, d1, 0, 0, 0);
            }
        }
        pk0[0] = cvt_pk_bf16(tanh_fast(d0[0]), tanh_fast(d0[1]));
        pk0[1] = cvt_pk_bf16(tanh_fast(d0[2]), tanh_fast(d0[3]));
        pk1[0] = cvt_pk_bf16(tanh_fast(d1[0]), tanh_fast(d1[1]));
        pk1[1] = cvt_pk_bf16(tanh_fast(d1[2]), tanh_fast(d1[3]));
        if (lr == 0) {
            *(u32x2*)&h1s[nxt][n0 + lg * 4] = pk0;
            *(u32x2*)&h1s[nxt][n0 + 16 + lg * 4] = pk1;
            *(u32x2*)h1p        = pk0;
            *(u32x2*)(h1p + 16) = pk1;
        }
        h1p += B_ * H_;

        cur = nxt;
    }
}

// -------- kernel 3 (swapped): Y[b][t][d] = bout[d] + sum_k H1[t][b][k]*Wout[d][k]
__global__ __launch_bounds__(256) void k_out(const unsigned short* __restrict__ H1,
                                             const float* __restrict__ Wout,
                                             const float* __restrict__ bout,
                                             float* __restrict__ out) {
    const int t  = blockIdx.x;
    const int bc = blockIdx.y;
    const int w  = threadIdx.x >> 6;
    const int l  = threadIdx.x & 63;
    const int lr = l & 15, lg = l >> 4;

    bf16x8 af[8];
    const unsigned short* hrow = H1 + ((size_t)t * B_ + bc * 16 + lr) * H_ + lg * 8;
#pragma unroll
    for (int kk = 0; kk < 8; kk++)
        af[kk] = __builtin_bit_cast(bf16x8, *(const u16x8*)(hrow + kk * 32));

#pragma unroll
    for (int i = 0; i < 2; i++) {
        const int n0 = (w + 4 * i) * 16;
        const float* wrow = Wout + (size_t)(n0 + lr) * H_ + lg * 8;
        float4 bv = *(const float4*)&bout[n0 + lg * 4];
        f32x4 acc = { bv.x, bv.y, bv.z, bv.w };
#pragma unroll
        for (int kk = 0; kk < 8; kk++) {
            bf16x8 bfr = ld8f_bf(wrow + kk * 32);
            acc = __builtin_amdgcn_mfma_f32_16x16x32_bf16(bfr, af[kk], acc, 0, 0, 0);
        }
        *(f32x4*)&out[((size_t)(bc * 16 + lr) * T_ + t) * DOUT_ + n0 + lg * 4] = acc;
    }
}

extern "C" void kernel_launch(void* const* d_in, const int* in_sizes, int n_in,
                              void* d_out, int out_size, void* d_ws, size_t ws_size,
                              hipStream_t stream) {
    const float* x    = (const float*)d_in[0];
    const float* h0   = (const float*)d_in[1];
    const float* Wx0  = (const float*)d_in[2];
    const float* Wh0  = (const float*)d_in[3];
    const float* b0   = (const float*)d_in[4];
    const float* Wx1  = (const float*)d_in[5];
    const float* Wh1  = (const float*)d_in[6];
    const float* b1   = (const float*)d_in[7];
    const float* Wout = (const float*)d_in[8];
    const float* bout = (const float*)d_in[9];
    float* out = (float*)d_out;

    unsigned short* Pre0 = (unsigned short*)d_ws;
    unsigned short* H1   = Pre0 + (size_t)T_ * B_ * H_;

    k_pre<<<dim3(T_, B_ / 16), 256, 0, stream>>>(x, Wx0, b0, Pre0);
    k_scan<<<dim3(B_), 512, 0, stream>>>(h0, Wh0, Wx1, Wh1, b1, Pre0, H1);
    k_out<<<dim3(T_, B_ / 16), 256, 0, stream>>>(H1, Wout, bout, out);
}

// Round 10
// 2728.248 us; speedup vs baseline: 1.2309x; 1.2309x over previous
//
#include <hip/hip_runtime.h>
#include <hip/hip_bf16.h>

#define B_ 64
#define T_ 2048
#define DIN_ 128
#define H_ 256
#define DOUT_ 128

typedef __bf16 bf16x8 __attribute__((ext_vector_type(8)));
typedef unsigned short u16x8 __attribute__((ext_vector_type(8)));
typedef unsigned int u32x2 __attribute__((ext_vector_type(2)));
typedef unsigned int u32x4 __attribute__((ext_vector_type(4)));
typedef float f32x4 __attribute__((ext_vector_type(4)));

static __device__ __forceinline__ unsigned short f2bf(float f) {
    union { float f; unsigned u; } v; v.f = f;
    unsigned r = v.u + 0x7FFFu + ((v.u >> 16) & 1u);   // RNE
    return (unsigned short)(r >> 16);
}
static __device__ __forceinline__ unsigned cvt_pk_bf16(float lo, float hi) {
    unsigned r;
    asm("v_cvt_pk_bf16_f32 %0, %1, %2" : "=v"(r) : "v"(lo), "v"(hi));
    return r;
}
static __device__ __forceinline__ float bfbits_lo(unsigned w) {
    union { unsigned u; float f; } v; v.u = w << 16; return v.f;
}
static __device__ __forceinline__ float bfbits_hi(unsigned w) {
    union { unsigned u; float f; } v; v.u = w & 0xFFFF0000u; return v.f;
}
static __device__ __forceinline__ float tanh_fast(float x) {
    // tanh(x) = 1 - 2/(exp2(2*log2e*x)+1); branch-free, no clamp, no NaN
    float e = __builtin_amdgcn_exp2f(2.885390081777927f * x);
    float r = __builtin_amdgcn_rcpf(e + 1.0f);
    return __builtin_fmaf(-2.0f, r, 1.0f);
}
static __device__ __forceinline__ bf16x8 ld8f_bf(const float* p) {
    float4 a = *(const float4*)p;
    float4 b = *(const float4*)(p + 4);
    u32x4 u;
    u[0] = cvt_pk_bf16(a.x, a.y);
    u[1] = cvt_pk_bf16(a.z, a.w);
    u[2] = cvt_pk_bf16(b.x, b.y);
    u[3] = cvt_pk_bf16(b.z, b.w);
    return __builtin_bit_cast(bf16x8, u);
}

// -------- kernel 1 (swapped): Pre0[t][b][n] = b0[n] + sum_k x[b][t][k]*Wx0[n][k]
__global__ __launch_bounds__(256) void k_pre(const float* __restrict__ x,
                                             const float* __restrict__ Wx0,
                                             const float* __restrict__ b0,
                                             unsigned short* __restrict__ Pre0) {
    const int t  = blockIdx.x;
    const int bc = blockIdx.y;
    const int w  = threadIdx.x >> 6;
    const int l  = threadIdx.x & 63;
    const int lr = l & 15, lg = l >> 4;

    bf16x8 af[4];
    const float* xrow = x + ((size_t)(bc * 16 + lr) * T_ + t) * DIN_ + lg * 8;
#pragma unroll
    for (int kk = 0; kk < 4; kk++) af[kk] = ld8f_bf(xrow + kk * 32);

    unsigned short* op = Pre0 + ((size_t)t * B_ + bc * 16 + lr) * H_;

#pragma unroll
    for (int i = 0; i < 4; i++) {
        const int n0 = (w + 4 * i) * 16;
        const float* wrow = Wx0 + (size_t)(n0 + lr) * DIN_ + lg * 8;
        bf16x8 bfr[4];
#pragma unroll
        for (int kk = 0; kk < 4; kk++) bfr[kk] = ld8f_bf(wrow + kk * 32);
        float4 bv = *(const float4*)&b0[n0 + lg * 4];
        f32x4 acc = { bv.x, bv.y, bv.z, bv.w };
#pragma unroll
        for (int kk = 0; kk < 4; kk++)
            acc = __builtin_amdgcn_mfma_f32_16x16x32_bf16(bfr[kk], af[kk], acc, 0, 0, 0);
        u32x2 pk;
        pk[0] = cvt_pk_bf16(acc[0], acc[1]);
        pk[1] = cvt_pk_bf16(acc[2], acc[3]);
        *(u32x2*)&op[n0 + lg * 4] = pk;
    }
}

// -------- kernel 2: sequential scan. 64 blocks x ONE batch row; 16 waves x 16 n.
// M=1: all lane-groups read the SAME state chunk (LDS broadcast, 0 conflicts).
// 16 waves => only 96 weight regs/wave + ~28 working: fits the 128-reg budget
// the compiler enforces at 4 waves/SIMD. Pure intrinsics: no AGPR banking,
// no shuttles, no inline asm, compiler-managed hazards. 1 barrier/step.
__global__ __launch_bounds__(1024)
void k_scan(const float* __restrict__ h0in,
            const float* __restrict__ Wh0,
            const float* __restrict__ Wx1,
            const float* __restrict__ Wh1,
            const float* __restrict__ b1,
            const unsigned short* __restrict__ Pre0,
            unsigned short* __restrict__ H1) {
    const int b   = blockIdx.x;            // one batch row per block
    const int tid = threadIdx.x;
    const int w   = tid >> 6, l = tid & 63;
    const int lr  = l & 15, lg = l >> 4;
    const int n0  = w * 16;                // 16 output cols per wave

    __shared__ __align__(16) unsigned short h0s[2][256];
    __shared__ __align__(16) unsigned short h1s[2][256];

    // weight fragments: lane = W[n = n0+lr][k = kk*32+lg*8 .. +7]  (96 VGPRs)
    bf16x8 wh0f[8], wx1f[8], wh1f[8];
    {
        const int n = n0 + lr;
#pragma unroll
        for (int kk = 0; kk < 8; kk++) {
            const int k0 = kk * 32 + lg * 8;
            wh0f[kk] = ld8f_bf(Wh0 + (size_t)n * H_ + k0);
            wx1f[kk] = ld8f_bf(Wx1 + (size_t)n * H_ + k0);
            wh1f[kk] = ld8f_bf(Wh1 + (size_t)n * H_ + k0);
        }
    }
    float4 b1q = *(const float4*)&b1[n0 + lg * 4];

    // init state (linear, no swizzle)
    if (tid < 256) {
        h0s[0][tid] = f2bf(h0in[(size_t)b * H_ + tid]);
        h1s[0][tid] = f2bf(h0in[(size_t)(B_ + b) * H_ + tid]);
    }

    // Pre0 / H1 pointers (uniform across lr within a lane-group)
    const unsigned short* prep = Pre0 + (size_t)b * H_ + n0 + lg * 4;
    unsigned short* h1p = H1 + (size_t)b * H_ + n0 + lg * 4;
    u32x2 pv = *(const u32x2*)prep;
    prep += B_ * H_;

    __syncthreads();

    int cur = 0;
    for (int t = 0; t < T_; t++) {
        const int nxt = cur ^ 1;
        // ---- layer 0: h0n^T = Wh0 . h0^T + Pre0^T  (one C->C chain)
        f32x4 a0;
        a0[0] = bfbits_lo(pv[0]); a0[1] = bfbits_hi(pv[0]);
        a0[2] = bfbits_lo(pv[1]); a0[3] = bfbits_hi(pv[1]);
        // prefetch next step's Pre0 (tail over-read lands in H1 region, harmless)
        pv = *(const u32x2*)prep;
        prep += B_ * H_;
#pragma unroll
        for (int kk = 0; kk < 8; kk++) {
            bf16x8 s = __builtin_bit_cast(bf16x8, *(const u16x8*)&h0s[cur][kk * 32 + lg * 8]);
            a0 = __builtin_amdgcn_mfma_f32_16x16x32_bf16(wh0f[kk], s, a0, 0, 0, 0);
        }
        u32x2 pk;
        pk[0] = cvt_pk_bf16(tanh_fast(a0[0]), tanh_fast(a0[1]));
        pk[1] = cvt_pk_bf16(tanh_fast(a0[2]), tanh_fast(a0[3]));
        if (lr == 0) {
            *(u32x2*)&h0s[nxt][n0 + lg * 4] = pk;
        }

        __syncthreads();   // single barrier per step (other pairs ordered by next one)

        // ---- layer 1: h1n^T = Wx1 . h0n^T + Wh1 . h1^T + b1  (one C->C chain)
        f32x4 d0 = { b1q.x, b1q.y, b1q.z, b1q.w };
#pragma unroll
        for (int kk = 0; kk < 8; kk++) {
            bf16x8 s0 = __builtin_bit_cast(bf16x8, *(const u16x8*)&h0s[nxt][kk * 32 + lg * 8]);
            d0 = __builtin_amdgcn_mfma_f32_16x16x32_bf16(wx1f[kk], s0, d0, 0, 0, 0);
            bf16x8 s1 = __builtin_bit_cast(bf16x8, *(const u16x8*)&h1s[cur][kk * 32 + lg * 8]);
            d0 = __builtin_amdgcn_mfma_f32_16x16x32_bf16(wh1f[kk], s1, d0, 0, 0, 0);
        }
        pk[0] = cvt_pk_bf16(tanh_fast(d0[0]), tanh_fast(d0[1]));
        pk[1] = cvt_pk_bf16(tanh_fast(d0[2]), tanh_fast(d0[3]));
        if (lr == 0) {
            *(u32x2*)&h1s[nxt][n0 + lg * 4] = pk;
            *(u32x2*)h1p = pk;
        }
        h1p += B_ * H_;

        cur = nxt;
    }
}

// -------- kernel 3 (swapped): Y[b][t][d] = bout[d] + sum_k H1[t][b][k]*Wout[d][k]
__global__ __launch_bounds__(256) void k_out(const unsigned short* __restrict__ H1,
                                             const float* __restrict__ Wout,
                                             const float* __restrict__ bout,
                                             float* __restrict__ out) {
    const int t  = blockIdx.x;
    const int bc = blockIdx.y;
    const int w  = threadIdx.x >> 6;
    const int l  = threadIdx.x & 63;
    const int lr = l & 15, lg = l >> 4;

    bf16x8 af[8];
    const unsigned short* hrow = H1 + ((size_t)t * B_ + bc * 16 + lr) * H_ + lg * 8;
#pragma unroll
    for (int kk = 0; kk < 8; kk++)
        af[kk] = __builtin_bit_cast(bf16x8, *(const u16x8*)(hrow + kk * 32));

#pragma unroll
    for (int i = 0; i < 2; i++) {
        const int n0 = (w + 4 * i) * 16;
        const float* wrow = Wout + (size_t)(n0 + lr) * H_ + lg * 8;
        float4 bv = *(const float4*)&bout[n0 + lg * 4];
        f32x4 acc = { bv.x, bv.y, bv.z, bv.w };
#pragma unroll
        for (int kk = 0; kk < 8; kk++) {
            bf16x8 bfr = ld8f_bf(wrow + kk * 32);
            acc = __builtin_amdgcn_mfma_f32_16x16x32_bf16(bfr, af[kk], acc, 0, 0, 0);
        }
        *(f32x4*)&out[((size_t)(bc * 16 + lr) * T_ + t) * DOUT_ + n0 + lg * 4] = acc;
    }
}

extern "C" void kernel_launch(void* const* d_in, const int* in_sizes, int n_in,
                              void* d_out, int out_size, void* d_ws, size_t ws_size,
                              hipStream_t stream) {
    const float* x    = (const float*)d_in[0];
    const float* h0   = (const float*)d_in[1];
    const float* Wx0  = (const float*)d_in[2];
    const float* Wh0  = (const float*)d_in[3];
    const float* b0   = (const float*)d_in[4];
    const float* Wx1  = (const float*)d_in[5];
    const float* Wh1  = (const float*)d_in[6];
    const float* b1   = (const float*)d_in[7];
    const float* Wout = (const float*)d_in[8];
    const float* bout = (const float*)d_in[9];
    float* out = (float*)d_out;

    unsigned short* Pre0 = (unsigned short*)d_ws;
    unsigned short* H1   = Pre0 + (size_t)T_ * B_ * H_;

    k_pre<<<dim3(T_, B_ / 16), 256, 0, stream>>>(x, Wx0, b0, Pre0);
    k_scan<<<dim3(B_), 1024, 0, stream>>>(h0, Wh0, Wx1, Wh1, b1, Pre0, H1);
    k_out<<<dim3(T_, B_ / 16), 256, 0, stream>>>(H1, Wout, bout, out);
}